// Round 2
// baseline (3108.071 us; speedup 1.0000x reference)
//
#include <hip/hip_runtime.h>
#include <math.h>

#define SEQ    1024
#define EMBED  300
#define HIDDEN 512
#define G4     2048          // 4*HIDDEN, gate order i,f,g,o
#define NB     32            // persistent blocks in phase 2
#define UPB    (HIDDEN/NB)   // hidden units owned per block = 16
#define PAD_IDX 1
#define SENT   0x7FC00BADu   // NaN bit-pattern sentinel: never produced by
                             // real LSTM math (outputs always finite)

// ---- device-global scratch. Fully re-initialized by phase 1 every call:
// g_h filled with sentinel (+h0 in slot 0), g_xg fully overwritten. ----
__device__ float g_xg[SEQ * G4];            // x @ W_ih^T + b_ih + b_hh
__device__ float g_h[(SEQ + 1) * HIDDEN];   // per-step h broadcast buffers

__device__ __forceinline__ float sigmoidf_(float x) {
    return 1.f / (1.f + __expf(-x));
}

// ---------------------------------------------------------------------------
// Phase 1: xg[t][k] = dot(emb[token[t]], W_ih[k]) + b_ih[k] + b_hh[k]
// grid = 256 blocks (128 t-tiles of 8 tokens x 2 k-halves), 256 threads.
// Also re-inits g_h: slot 0 = h0, slots 1..SEQ = sentinel. Kernel boundary
// makes all of this coherently visible to phase 2.
// ---------------------------------------------------------------------------
__global__ __launch_bounds__(256) void xgates_kernel(
    const int* __restrict__ seq, const float* __restrict__ h0,
    const float* __restrict__ emb, const float* __restrict__ W_ih,
    const float* __restrict__ b_ih, const float* __restrict__ b_hh)
{
    const int bx = blockIdx.x, tid = threadIdx.x;

    // grid-strided init of g_h (525312 floats / 65536 threads = 9 iters)
    for (int i = bx * 256 + tid; i < (SEQ + 1) * HIDDEN; i += 256 * 256) {
        g_h[i] = (i < HIDDEN) ? h0[i] : __uint_as_float(SENT);
    }

    const int t_tile = bx >> 1, k_half = bx & 1;
    const int t0 = t_tile * 8;

    __shared__ int tok_s[8];
    __shared__ __align__(16) float embt[8][304]; // 304: pad keeps float4 align

    if (tid < 8) tok_s[tid] = seq[t0 + tid];
    __syncthreads();
    for (int idx = tid; idx < 8 * EMBED; idx += 256) {
        int tt = idx / EMBED;
        int e  = idx - tt * EMBED;
        embt[tt][e] = emb[(size_t)tok_s[tt] * EMBED + e];
    }
    __syncthreads();

    const int kbase = k_half * 1024 + tid;
    const float4* wr0 = (const float4*)(W_ih + (size_t)(kbase      ) * EMBED);
    const float4* wr1 = (const float4*)(W_ih + (size_t)(kbase + 256) * EMBED);
    const float4* wr2 = (const float4*)(W_ih + (size_t)(kbase + 512) * EMBED);
    const float4* wr3 = (const float4*)(W_ih + (size_t)(kbase + 768) * EMBED);

    float acc[4][8];
    #pragma unroll
    for (int kk = 0; kk < 4; kk++)
        #pragma unroll
        for (int tt = 0; tt < 8; tt++) acc[kk][tt] = 0.f;

    for (int e4 = 0; e4 < EMBED / 4; e4++) {  // 75 iters
        float4 em[8];
        #pragma unroll
        for (int tt = 0; tt < 8; tt++)
            em[tt] = *(const float4*)&embt[tt][e4 * 4];
        float4 w[4];
        w[0] = wr0[e4]; w[1] = wr1[e4]; w[2] = wr2[e4]; w[3] = wr3[e4];
        #pragma unroll
        for (int kk = 0; kk < 4; kk++) {
            #pragma unroll
            for (int tt = 0; tt < 8; tt++) {
                float a = acc[kk][tt];
                a = fmaf(w[kk].x, em[tt].x, a);
                a = fmaf(w[kk].y, em[tt].y, a);
                a = fmaf(w[kk].z, em[tt].z, a);
                a = fmaf(w[kk].w, em[tt].w, a);
                acc[kk][tt] = a;
            }
        }
    }
    #pragma unroll
    for (int kk = 0; kk < 4; kk++) {
        int k = kbase + kk * 256;
        float bias = b_ih[k] + b_hh[k];
        #pragma unroll
        for (int tt = 0; tt < 8; tt++)
            g_xg[(size_t)(t0 + tt) * G4 + k] = acc[kk][tt] + bias;
    }
}

// ---------------------------------------------------------------------------
// Phase 2: persistent cooperative LSTM recurrence, barrier-free.
// 32 blocks x 256 threads. Sync = data-as-signal: per-step h buffers start
// as sentinel; consumers poll their 2 floats until non-sentinel (value-
// carried dependency -> no fences). One L3 round-trip per step.
//
// Thread map: tid = u*16 + g*4 + c  (u=unit 0..15, g=gate, c=col chunk).
// A unit's 4 gates live in 16 consecutive lanes of ONE wave -> gate combine
// via __shfl, no LDS round-trip, one __syncthreads per step (h_lds staging,
// double-buffered by step parity).
// W_hh row (g*512 + b*16 + u), chunk c (cols c*128..+128) lives in VGPRs
// (32 float4), traversal rotated by 4c so the 4 distinct per-instr LDS
// broadcast addresses hit disjoint bank groups (conflict-free).
// ---------------------------------------------------------------------------
__global__ __launch_bounds__(256, 1) void lstm_kernel(
    const int* __restrict__ seq, const float* __restrict__ h0,
    const float* __restrict__ c0, const float* __restrict__ Whh,
    float* __restrict__ out)
{
    const int b = blockIdx.x, tid = threadIdx.x;
    const int u = tid >> 4, r = tid & 15, g = r >> 2, c = r & 3;
    const int R = g * HIDDEN + b * UPB + u;

    const float* wrow = Whh + (size_t)R * HIDDEN + c * 128;
    float4 wreg[32];
    #pragma unroll
    for (int i = 0; i < 32; i++) {
        int off = (4 * i + 4 * c) & 127;   // rotated traversal
        wreg[i] = *(const float4*)(wrow + off);
    }

    __shared__ __align__(16) float h_lds[2][HIDDEN];

    const bool owner = (r == 0);
    float c_state = 0.f, h_state = 0.f;
    if (owner) {
        c_state = c0[b * UPB + u];
        h_state = h0[b * UPB + u];
    }

    const int lane = tid & 63;
    const int base = lane & ~15;   // first lane of this unit's 16-lane group

    int np = 0;                    // non-pad steps completed
    bool any = false;

    for (int t = 0; t < SEQ; t++) {
        int tok = seq[t];                 // uniform scalar load
        if (tok == PAD_IDX) continue;     // uniform across grid
        any = true;

        // prefetch input-gate contributions (independent of h)
        float xi = 0.f, xf = 0.f, xgg = 0.f, xo = 0.f;
        if (owner) {
            const float* xr = g_xg + (size_t)t * G4 + b * UPB + u;
            xi  = xr[0];
            xf  = xr[HIDDEN];
            xgg = xr[2 * HIDDEN];
            xo  = xr[3 * HIDDEN];
        }

        // poll-and-stage h: the value itself is the ready flag
        {
            const unsigned* hb = (const unsigned*)(g_h + (size_t)np * HIDDEN);
            unsigned v0, v1;
            do {
                v0 = __hip_atomic_load(hb + 2 * tid, __ATOMIC_RELAXED,
                                       __HIP_MEMORY_SCOPE_AGENT);
            } while (v0 == SENT);
            do {
                v1 = __hip_atomic_load(hb + 2 * tid + 1, __ATOMIC_RELAXED,
                                       __HIP_MEMORY_SCOPE_AGENT);
            } while (v1 == SENT);
            h_lds[np & 1][2 * tid]     = __uint_as_float(v0);
            h_lds[np & 1][2 * tid + 1] = __uint_as_float(v1);
        }
        __syncthreads();   // the only barrier per step

        // 128-length partial dot: W from VGPRs, h via LDS broadcasts
        const float* hc = h_lds[np & 1] + c * 128;
        float4 a4 = {0.f, 0.f, 0.f, 0.f};
        #pragma unroll
        for (int i = 0; i < 32; i++) {
            int off = (4 * i + 4 * c) & 127;
            float4 h4 = *(const float4*)(hc + off);
            a4.x = fmaf(wreg[i].x, h4.x, a4.x);
            a4.y = fmaf(wreg[i].y, h4.y, a4.y);
            a4.z = fmaf(wreg[i].z, h4.z, a4.z);
            a4.w = fmaf(wreg[i].w, h4.w, a4.w);
        }
        float dotv = (a4.x + a4.y) + (a4.z + a4.w);
        dotv += __shfl_xor(dotv, 1);   // reduce over c
        dotv += __shfl_xor(dotv, 2);   // c==0 lanes hold row dots

        // gather the 4 gate dots for this unit (all wave-local)
        float d0 = __shfl(dotv, base + 0);
        float d1 = __shfl(dotv, base + 4);
        float d2 = __shfl(dotv, base + 8);
        float d3 = __shfl(dotv, base + 12);

        if (owner) {
            float iv = sigmoidf_(xi  + d0);
            float fv = sigmoidf_(xf  + d1);
            float gv = tanhf    (xgg + d2);
            float ov = sigmoidf_(xo  + d3);
            c_state = fv * c_state + iv * gv;
            h_state = ov * tanhf(c_state);
            // publish: relaxed store, value is its own ready flag
            __hip_atomic_store((unsigned*)(g_h + (size_t)(np + 1) * HIDDEN
                                           + b * UPB + u),
                               __float_as_uint(h_state),
                               __ATOMIC_RELAXED, __HIP_MEMORY_SCOPE_AGENT);
        }
        np++;
    }

    if (owner) {
        int uo = b * UPB + u;
        out[uo]              = any ? h_state : 0.f;  // out
        out[HIDDEN + uo]     = h_state;              // h_final
        out[2 * HIDDEN + uo] = c_state;              // c_final
    }
}

// ---------------------------------------------------------------------------
extern "C" void kernel_launch(void* const* d_in, const int* in_sizes, int n_in,
                              void* d_out, int out_size, void* d_ws, size_t ws_size,
                              hipStream_t stream)
{
    const int*   seq  = (const int*)  d_in[0];
    const float* h0   = (const float*)d_in[1];
    const float* c0   = (const float*)d_in[2];
    const float* emb  = (const float*)d_in[3];
    const float* W_ih = (const float*)d_in[4];
    const float* W_hh = (const float*)d_in[5];
    const float* b_ih = (const float*)d_in[6];
    const float* b_hh = (const float*)d_in[7];
    float* out = (float*)d_out;

    hipLaunchKernelGGL(xgates_kernel, dim3(256), dim3(256), 0, stream,
                       seq, h0, emb, W_ih, b_ih, b_hh);

    void* args[] = { (void*)&seq, (void*)&h0, (void*)&c0, (void*)&W_hh, (void*)&out };
    hipLaunchCooperativeKernel((const void*)lstm_kernel, dim3(NB), dim3(256),
                               args, 0, stream);
}